// Round 1
// baseline (545.777 us; speedup 1.0000x reference)
//
#include <hip/hip_runtime.h>
#include <stdint.h>

#define MROWS 8192   // B*S
#define DM    1024
#define NH    16
#define HD    64
#define SEQ   2048

typedef __bf16 bf16x8 __attribute__((ext_vector_type(8)));
typedef __bf16 bf16x4 __attribute__((ext_vector_type(4)));
typedef float  floatx4 __attribute__((ext_vector_type(4)));

__device__ __forceinline__ void async16(const void* g, void* l) {
  __builtin_amdgcn_global_load_lds(
      (__attribute__((address_space(1))) void*)g,
      (__attribute__((address_space(3))) void*)l,
      16, 0, 0);
}

__device__ __forceinline__ floatx4 mfma16(bf16x8 a, bf16x8 b, floatx4 c) {
  return __builtin_amdgcn_mfma_f32_16x16x32_bf16(a, b, c, 0, 0, 0);
}

// ---------------- conversion kernels ----------------

// x fp32 -> hi/lo bf16 split (elementwise, float4 vectorized)
__global__ void __launch_bounds__(256) split_x_kernel(const float* __restrict__ x,
                                                      __bf16* __restrict__ xh,
                                                      __bf16* __restrict__ xl) {
  const int i = blockIdx.x * 256 + threadIdx.x;
  const float4 v = reinterpret_cast<const float4*>(x)[i];
  const float vv[4] = {v.x, v.y, v.z, v.w};
  bf16x4 H, L;
#pragma unroll
  for (int j = 0; j < 4; ++j) {
    const __bf16 h = (__bf16)vv[j];
    H[j] = h;
    L[j] = (__bf16)(vv[j] - (float)h);
  }
  reinterpret_cast<bf16x4*>(xh)[i] = H;
  reinterpret_cast<bf16x4*>(xl)[i] = L;
}

// W [K=1024][N=1024] fp32 -> W^T [N][K] bf16 hi (+ optional lo)
__global__ void __launch_bounds__(256) wtrans_kernel(const float* __restrict__ W,
                                                     __bf16* __restrict__ Th,
                                                     __bf16* __restrict__ Tl) {
  __shared__ float t[32][33];
  const int tx = threadIdx.x & 31, ty = threadIdx.x >> 5;  // tx 0..31, ty 0..7
  const int bx = blockIdx.x & 31, by = blockIdx.x >> 5;    // n-tile, k-tile
#pragma unroll
  for (int j = 0; j < 4; ++j) {
    const int k = by * 32 + ty + j * 8;
    t[ty + j * 8][tx] = W[(size_t)k * DM + bx * 32 + tx];
  }
  __syncthreads();
#pragma unroll
  for (int j = 0; j < 4; ++j) {
    const int n = bx * 32 + ty + j * 8;
    const int k = by * 32 + tx;
    const float v = t[tx][ty + j * 8];
    const __bf16 h = (__bf16)v;
    Th[(size_t)n * DM + k] = h;
    if (Tl) Tl[(size_t)n * DM + k] = (__bf16)(v - (float)h);
  }
}

// ---------------- NT GEMM: C[M,N] = A[M,K] * B^T  (B given as [N,K]) ----------------
// TERMS==3: 3-term hi/lo split product (drops lo*lo).
// OUTMODE: 0 = bf16 store, 1 = fp32 store, 2 = bf16 hi/lo split store,
//          3 = bf16 store transposed per-head: Vt[b,h,d,s]
template <int TERMS, int OUTMODE>
__global__ void __launch_bounds__(256) gemm_nt(const __bf16* __restrict__ Ah,
                                               const __bf16* __restrict__ Al,
                                               const __bf16* __restrict__ Bh,
                                               const __bf16* __restrict__ Bl,
                                               void* __restrict__ C0,
                                               void* __restrict__ C1) {
  __shared__ __align__(16) __bf16 sAh[128 * 32];
  __shared__ __align__(16) __bf16 sBh[128 * 32];
  __shared__ __align__(16) __bf16 sAl[(TERMS == 3) ? 128 * 32 : 8];
  __shared__ __align__(16) __bf16 sBl[(TERMS == 3) ? 128 * 32 : 8];

  const int tid = threadIdx.x;
  const int bm = blockIdx.x >> 3;   // M/128 = 64
  const int bn = blockIdx.x & 7;    // N/128 = 8
  const int m0 = bm << 7, n0 = bn << 7;
  const int w = tid >> 6;
  const int lane = tid & 63;
  const int wm = (w >> 1) << 6;     // wave 2x2 over 128x128
  const int wn = (w & 1) << 6;
  const int lm = lane & 15;
  const int q4 = lane >> 4;

  floatx4 acc[4][4];
  const floatx4 fz = {0.f, 0.f, 0.f, 0.f};
#pragma unroll
  for (int i = 0; i < 4; ++i)
#pragma unroll
    for (int j = 0; j < 4; ++j) acc[i][j] = fz;

  // staging geometry: chunk c = tid + r*256 ; row=c>>2 ; global chunk = (c&3) ^ ((row>>1)&3)
  const int c0 = tid, c1 = tid + 256;
  const int row0 = c0 >> 2, cc0 = (c0 & 3) ^ ((row0 >> 1) & 3);
  const int row1 = c1 >> 2, cc1 = (c1 & 3) ^ ((row1 >> 1) & 3);

  // fragment LDS offsets (swizzle-matched)
  int offA[4], offB[4];
#pragma unroll
  for (int i = 0; i < 4; ++i) {
    const int ra = wm + i * 16 + lm;
    offA[i] = ra * 32 + ((q4 ^ ((ra >> 1) & 3)) << 3);
    const int rb = wn + i * 16 + lm;
    offB[i] = rb * 32 + ((q4 ^ ((rb >> 1) & 3)) << 3);
  }

  for (int it = 0; it < 32; ++it) {
    const int k0 = it << 5;
    {
      const size_t ga0 = (size_t)(m0 + row0) * DM + k0 + cc0 * 8;
      const size_t gb0 = (size_t)(n0 + row0) * DM + k0 + cc0 * 8;
      const size_t ga1 = (size_t)(m0 + row1) * DM + k0 + cc1 * 8;
      const size_t gb1 = (size_t)(n0 + row1) * DM + k0 + cc1 * 8;
      async16(Ah + ga0, &sAh[c0 * 8]);
      async16(Bh + gb0, &sBh[c0 * 8]);
      async16(Ah + ga1, &sAh[c1 * 8]);
      async16(Bh + gb1, &sBh[c1 * 8]);
      if constexpr (TERMS == 3) {
        async16(Al + ga0, &sAl[c0 * 8]);
        async16(Bl + gb0, &sBl[c0 * 8]);
        async16(Al + ga1, &sAl[c1 * 8]);
        async16(Bl + gb1, &sBl[c1 * 8]);
      }
    }
    __syncthreads();  // drains vmcnt -> LDS ready

    bf16x8 ah[4], bh[4], al[4], bl[4];
#pragma unroll
    for (int i = 0; i < 4; ++i) {
      ah[i] = *(const bf16x8*)&sAh[offA[i]];
      bh[i] = *(const bf16x8*)&sBh[offB[i]];
      if constexpr (TERMS == 3) {
        al[i] = *(const bf16x8*)&sAl[offA[i]];
        bl[i] = *(const bf16x8*)&sBl[offB[i]];
      }
    }
#pragma unroll
    for (int i = 0; i < 4; ++i)
#pragma unroll
      for (int j = 0; j < 4; ++j) {
        acc[i][j] = mfma16(ah[i], bh[j], acc[i][j]);
        if constexpr (TERMS == 3) {
          acc[i][j] = mfma16(ah[i], bl[j], acc[i][j]);
          acc[i][j] = mfma16(al[i], bh[j], acc[i][j]);
        }
      }
    __syncthreads();
  }

  // epilogue; C/D layout: col = lane&15, row = (lane>>4)*4 + reg
#pragma unroll
  for (int i = 0; i < 4; ++i) {
#pragma unroll
    for (int j = 0; j < 4; ++j) {
#pragma unroll
      for (int r = 0; r < 4; ++r) {
        const int gr = m0 + wm + i * 16 + q4 * 4 + r;
        const int gc = n0 + wn + j * 16 + lm;
        const float v = acc[i][j][r];
        if constexpr (OUTMODE == 0) {
          ((__bf16*)C0)[(size_t)gr * DM + gc] = (__bf16)v;
        } else if constexpr (OUTMODE == 1) {
          ((float*)C0)[(size_t)gr * DM + gc] = v;
        } else if constexpr (OUTMODE == 2) {
          const __bf16 hv = (__bf16)v;
          ((__bf16*)C0)[(size_t)gr * DM + gc] = hv;
          ((__bf16*)C1)[(size_t)gr * DM + gc] = (__bf16)(v - (float)hv);
        } else {
          const int bb = gr >> 11, ss = gr & 2047;
          const int hh = gc >> 6, dd = gc & 63;
          ((__bf16*)C0)[(((size_t)(bb * NH + hh) << 6) + dd) * SEQ + ss] = (__bf16)v;
        }
      }
    }
  }
}

// ---------------- flash attention ----------------
// grid: blockIdx.x = bh*32 + qtile ; block = 256 (4 waves, each wave owns 16 q rows)
__global__ void __launch_bounds__(256) flash_kernel(const __bf16* __restrict__ Qh,
                                                    const __bf16* __restrict__ Ql,
                                                    const __bf16* __restrict__ Kh,
                                                    const __bf16* __restrict__ Kl,
                                                    const __bf16* __restrict__ Vt,
                                                    __bf16* __restrict__ Mg) {
  __shared__ __align__(16) __bf16 sQh[64 * 64], sQl[64 * 64];
  __shared__ __align__(16) __bf16 sKh[64 * 64], sKl[64 * 64], sV[64 * 64];
  __shared__ __align__(16) __bf16 sP[4][16 * 80];

  const int tid = threadIdx.x;
  const int qt = blockIdx.x & 31;
  const int bh = blockIdx.x >> 5;
  const int b = bh >> 4;
  const int h = bh & 15;
  const int mq0 = b * SEQ + qt * 64;  // global Q row base
  const int ch = h * 64;              // column base for this head
  const int w = tid >> 6;
  const int lane = tid & 63;
  const int lm = lane & 15;
  const int q4 = lane >> 4;

  // stage Q tile [64 q][64 d], swizzle chunk ^ (row&7)
#pragma unroll
  for (int r = 0; r < 2; ++r) {
    const int c = tid + r * 256;
    const int row = c >> 3, cc = (c & 7) ^ (row & 7);
    const size_t g = (size_t)(mq0 + row) * DM + ch + cc * 8;
    async16(Qh + g, &sQh[c * 8]);
    async16(Ql + g, &sQl[c * 8]);
  }

  floatx4 o[4];
  const floatx4 fz = {0.f, 0.f, 0.f, 0.f};
#pragma unroll
  for (int dt = 0; dt < 4; ++dt) o[dt] = fz;
  float mrow[4], lrow[4];
#pragma unroll
  for (int r = 0; r < 4; ++r) { mrow[r] = -1e30f; lrow[r] = 0.f; }

  __syncthreads();  // Q staged

  for (int it = 0; it < 32; ++it) {
    const int kt0 = it * 64;
    // stage K tile [64 key][64 d] and V tile [64 d][64 key]
#pragma unroll
    for (int r = 0; r < 2; ++r) {
      const int c = tid + r * 256;
      const int row = c >> 3, cc = (c & 7) ^ (row & 7);
      const size_t gk = (size_t)(b * SEQ + kt0 + row) * DM + ch + cc * 8;
      async16(Kh + gk, &sKh[c * 8]);
      async16(Kl + gk, &sKl[c * 8]);
      const size_t gv = ((size_t)(bh * 64 + row)) * SEQ + kt0 + cc * 8;
      async16(Vt + gv, &sV[c * 8]);
    }
    __syncthreads();

    // scores: S[16 q x 64 key] per wave, 3-term
    floatx4 s[4];
#pragma unroll
    for (int nt = 0; nt < 4; ++nt) s[nt] = fz;
#pragma unroll
    for (int ks = 0; ks < 2; ++ks) {
      const int rq = w * 16 + lm;
      const int oq = rq * 64 + (((ks * 4 + q4) ^ (rq & 7)) << 3);
      const bf16x8 qh = *(const bf16x8*)&sQh[oq];
      const bf16x8 ql = *(const bf16x8*)&sQl[oq];
#pragma unroll
      for (int nt = 0; nt < 4; ++nt) {
        const int rk = nt * 16 + lm;
        const int ok = rk * 64 + (((ks * 4 + q4) ^ (rk & 7)) << 3);
        const bf16x8 kh = *(const bf16x8*)&sKh[ok];
        const bf16x8 kl = *(const bf16x8*)&sKl[ok];
        s[nt] = mfma16(qh, kh, s[nt]);
        s[nt] = mfma16(qh, kl, s[nt]);
        s[nt] = mfma16(ql, kh, s[nt]);
      }
    }

    // online softmax; lane's rows are q = q4*4 + r (C layout)
    float alpha[4];
#pragma unroll
    for (int r = 0; r < 4; ++r) {
      float mx = -1e30f;
#pragma unroll
      for (int nt = 0; nt < 4; ++nt) {
        s[nt][r] *= 0.125f;  // 1/sqrt(64)
        mx = fmaxf(mx, s[nt][r]);
      }
#pragma unroll
      for (int d = 1; d < 16; d <<= 1) mx = fmaxf(mx, __shfl_xor(mx, d));
      const float mnew = fmaxf(mrow[r], mx);
      alpha[r] = __expf(mrow[r] - mnew);
      float p[4], sum = 0.f;
#pragma unroll
      for (int nt = 0; nt < 4; ++nt) {
        p[nt] = __expf(s[nt][r] - mnew);
        sum += p[nt];
      }
#pragma unroll
      for (int d = 1; d < 16; d <<= 1) sum += __shfl_xor(sum, d);
      lrow[r] = lrow[r] * alpha[r] + sum;
      mrow[r] = mnew;
      const int qrow = q4 * 4 + r;
#pragma unroll
      for (int nt = 0; nt < 4; ++nt)
        sP[w][qrow * 80 + nt * 16 + lm] = (__bf16)p[nt];
    }

    // rescale O
#pragma unroll
    for (int dt = 0; dt < 4; ++dt)
#pragma unroll
      for (int r = 0; r < 4; ++r) o[dt][r] *= alpha[r];

    // PV: A = P (own wave's LDS), B = V^T tile
#pragma unroll
    for (int ks = 0; ks < 2; ++ks) {
      const bf16x8 a = *(const bf16x8*)&sP[w][lm * 80 + ((ks * 4 + q4) << 3)];
#pragma unroll
      for (int dt = 0; dt < 4; ++dt) {
        const int rv = dt * 16 + lm;
        const int ov = rv * 64 + (((ks * 4 + q4) ^ (rv & 7)) << 3);
        const bf16x8 bv = *(const bf16x8*)&sV[ov];
        o[dt] = mfma16(a, bv, o[dt]);
      }
    }
    __syncthreads();
  }

  // epilogue: normalize and store merged [B*S, D] bf16
#pragma unroll
  for (int r = 0; r < 4; ++r) {
    const float inv = 1.f / lrow[r];
    const int gr = mq0 + w * 16 + q4 * 4 + r;
#pragma unroll
    for (int dt = 0; dt < 4; ++dt)
      Mg[(size_t)gr * DM + ch + dt * 16 + lm] = (__bf16)(o[dt][r] * inv);
  }
}

// ---------------- launch ----------------

extern "C" void kernel_launch(void* const* d_in, const int* in_sizes, int n_in,
                              void* d_out, int out_size, void* d_ws, size_t ws_size,
                              hipStream_t stream) {
  (void)in_sizes; (void)n_in; (void)out_size; (void)ws_size;
  const float* x  = (const float*)d_in[0];
  const float* Wq = (const float*)d_in[1];
  const float* Wk = (const float*)d_in[2];
  const float* Wv = (const float*)d_in[3];
  const float* fc = (const float*)d_in[4];
  float* out = (float*)d_out;

  char* base = (char*)d_ws;
  const size_t XB = (size_t)MROWS * DM * 2;  // 16 MiB
  const size_t WB = (size_t)DM * DM * 2;     // 2 MiB
  __bf16* xh  = (__bf16*)(base);
  __bf16* xl  = (__bf16*)(base + XB);
  __bf16* wqh = (__bf16*)(base + 2 * XB);
  __bf16* wql = (__bf16*)(base + 2 * XB + WB);
  __bf16* wkh = (__bf16*)(base + 2 * XB + 2 * WB);
  __bf16* wkl = (__bf16*)(base + 2 * XB + 3 * WB);
  __bf16* wvh = (__bf16*)(base + 2 * XB + 4 * WB);
  __bf16* fch = (__bf16*)(base + 2 * XB + 5 * WB);
  __bf16* Qh  = (__bf16*)(base + 2 * XB + 6 * WB);
  __bf16* Ql  = (__bf16*)(base + 3 * XB + 6 * WB);
  __bf16* Kh  = (__bf16*)(base + 4 * XB + 6 * WB);
  __bf16* Kl  = (__bf16*)(base + 5 * XB + 6 * WB);
  __bf16* Vt  = xl;  // xl dead after K projection
  __bf16* Mg  = xh;  // xh dead after V projection

  split_x_kernel<<<dim3(8192), dim3(256), 0, stream>>>(x, xh, xl);
  wtrans_kernel<<<dim3(1024), dim3(256), 0, stream>>>(Wq, wqh, wql);
  wtrans_kernel<<<dim3(1024), dim3(256), 0, stream>>>(Wk, wkh, wkl);
  wtrans_kernel<<<dim3(1024), dim3(256), 0, stream>>>(Wv, wvh, (__bf16*)nullptr);
  wtrans_kernel<<<dim3(1024), dim3(256), 0, stream>>>(fc, fch, (__bf16*)nullptr);

  gemm_nt<3, 2><<<dim3(512), dim3(256), 0, stream>>>(xh, xl, wqh, wql, (void*)Qh, (void*)Ql);
  gemm_nt<3, 2><<<dim3(512), dim3(256), 0, stream>>>(xh, xl, wkh, wkl, (void*)Kh, (void*)Kl);
  gemm_nt<1, 3><<<dim3(512), dim3(256), 0, stream>>>(xh, (const __bf16*)nullptr, wvh,
                                                     (const __bf16*)nullptr, (void*)Vt, (void*)nullptr);

  flash_kernel<<<dim3(2048), dim3(256), 0, stream>>>(Qh, Ql, Kh, Kl, Vt, Mg);

  gemm_nt<1, 1><<<dim3(512), dim3(256), 0, stream>>>(Mg, (const __bf16*)nullptr, fch,
                                                     (const __bf16*)nullptr, (void*)out, (void*)nullptr);
}

// Round 2
// 473.108 us; speedup vs baseline: 1.1536x; 1.1536x over previous
//
#include <hip/hip_runtime.h>
#include <stdint.h>

#define MROWS 8192   // B*S
#define DM    1024
#define NH    16
#define HD    64
#define SEQ   2048

typedef __bf16 bf16x8 __attribute__((ext_vector_type(8)));
typedef __bf16 bf16x4 __attribute__((ext_vector_type(4)));
typedef float  floatx4 __attribute__((ext_vector_type(4)));

// 0.125 (1/sqrt(64)) * log2(e): folded into Q so flash scores are already base-2
#define QSCALE 0.18033688011112042f

__device__ __forceinline__ void async16(const void* g, void* l) {
  __builtin_amdgcn_global_load_lds(
      (__attribute__((address_space(1))) void*)g,
      (__attribute__((address_space(3))) void*)l,
      16, 0, 0);
}

__device__ __forceinline__ floatx4 mfma16(bf16x8 a, bf16x8 b, floatx4 c) {
  return __builtin_amdgcn_mfma_f32_16x16x32_bf16(a, b, c, 0, 0, 0);
}

// DPP lane-rotate/permute within 16-lane rows (pure VALU, no LDS)
template <int CTRL>
__device__ __forceinline__ float dpp_mov(float x) {
  return __builtin_bit_cast(float,
      __builtin_amdgcn_update_dpp(0, __builtin_bit_cast(int, x), CTRL, 0xF, 0xF, true));
}
// full 16-lane reductions: quad_perm(1,0,3,2)=0xB1, quad_perm(2,3,0,1)=0x4E,
// row_ror:4=0x124, row_ror:8=0x128
__device__ __forceinline__ float red16_max(float x) {
  x = fmaxf(x, dpp_mov<0xB1>(x));
  x = fmaxf(x, dpp_mov<0x4E>(x));
  x = fmaxf(x, dpp_mov<0x124>(x));
  x = fmaxf(x, dpp_mov<0x128>(x));
  return x;
}
__device__ __forceinline__ float red16_sum(float x) {
  x += dpp_mov<0xB1>(x);
  x += dpp_mov<0x4E>(x);
  x += dpp_mov<0x124>(x);
  x += dpp_mov<0x128>(x);
  return x;
}

// ---------------- conversion kernels ----------------

__global__ void __launch_bounds__(256) split_x_kernel(const float* __restrict__ x,
                                                      __bf16* __restrict__ xh,
                                                      __bf16* __restrict__ xl) {
  const int i = blockIdx.x * 256 + threadIdx.x;
  const float4 v = reinterpret_cast<const float4*>(x)[i];
  const float vv[4] = {v.x, v.y, v.z, v.w};
  bf16x4 H, L;
#pragma unroll
  for (int j = 0; j < 4; ++j) {
    const __bf16 h = (__bf16)vv[j];
    H[j] = h;
    L[j] = (__bf16)(vv[j] - (float)h);
  }
  reinterpret_cast<bf16x4*>(xh)[i] = H;
  reinterpret_cast<bf16x4*>(xl)[i] = L;
}

// W [K=1024][N=1024] fp32 -> W^T [N][K] bf16 hi (+ optional lo)
__global__ void __launch_bounds__(256) wtrans_kernel(const float* __restrict__ W,
                                                     __bf16* __restrict__ Th,
                                                     __bf16* __restrict__ Tl) {
  __shared__ float t[32][33];
  const int tx = threadIdx.x & 31, ty = threadIdx.x >> 5;
  const int bx = blockIdx.x & 31, by = blockIdx.x >> 5;
#pragma unroll
  for (int j = 0; j < 4; ++j) {
    const int k = by * 32 + ty + j * 8;
    t[ty + j * 8][tx] = W[(size_t)k * DM + bx * 32 + tx];
  }
  __syncthreads();
#pragma unroll
  for (int j = 0; j < 4; ++j) {
    const int n = bx * 32 + ty + j * 8;
    const int k = by * 32 + tx;
    const float v = t[tx][ty + j * 8];
    const __bf16 h = (__bf16)v;
    Th[(size_t)n * DM + k] = h;
    if (Tl) Tl[(size_t)n * DM + k] = (__bf16)(v - (float)h);
  }
}

// ---------------- NT GEMM: C[M,N] = A[M,K] * B^T  (B given as [N,K]) ----------------
// TERMS==3: 3-term hi/lo split product (drops lo*lo).
// OUTMODE: 0 = bf16, 1 = fp32, 2 = bf16 hi/lo split (scaled by oscale before split),
//          3 = bf16 transposed per-head: Vt[b,h,d,s]
template <int TERMS, int OUTMODE>
__global__ void __launch_bounds__(256) gemm_nt(const __bf16* __restrict__ Ah,
                                               const __bf16* __restrict__ Al,
                                               const __bf16* __restrict__ Bh,
                                               const __bf16* __restrict__ Bl,
                                               void* __restrict__ C0,
                                               void* __restrict__ C1,
                                               float oscale) {
  __shared__ __align__(16) __bf16 sAh[128 * 32];
  __shared__ __align__(16) __bf16 sBh[128 * 32];
  __shared__ __align__(16) __bf16 sAl[(TERMS == 3) ? 128 * 32 : 8];
  __shared__ __align__(16) __bf16 sBl[(TERMS == 3) ? 128 * 32 : 8];

  const int tid = threadIdx.x;
  const int bm = blockIdx.x >> 3;
  const int bn = blockIdx.x & 7;
  const int m0 = bm << 7, n0 = bn << 7;
  const int w = tid >> 6;
  const int lane = tid & 63;
  const int wm = (w >> 1) << 6;
  const int wn = (w & 1) << 6;
  const int lm = lane & 15;
  const int q4 = lane >> 4;

  floatx4 acc[4][4];
  const floatx4 fz = {0.f, 0.f, 0.f, 0.f};
#pragma unroll
  for (int i = 0; i < 4; ++i)
#pragma unroll
    for (int j = 0; j < 4; ++j) acc[i][j] = fz;

  const int c0 = tid, c1 = tid + 256;
  const int row0 = c0 >> 2, cc0 = (c0 & 3) ^ ((row0 >> 1) & 3);
  const int row1 = c1 >> 2, cc1 = (c1 & 3) ^ ((row1 >> 1) & 3);

  int offA[4], offB[4];
#pragma unroll
  for (int i = 0; i < 4; ++i) {
    const int ra = wm + i * 16 + lm;
    offA[i] = ra * 32 + ((q4 ^ ((ra >> 1) & 3)) << 3);
    const int rb = wn + i * 16 + lm;
    offB[i] = rb * 32 + ((q4 ^ ((rb >> 1) & 3)) << 3);
  }

  for (int it = 0; it < 32; ++it) {
    const int k0 = it << 5;
    {
      const size_t ga0 = (size_t)(m0 + row0) * DM + k0 + cc0 * 8;
      const size_t gb0 = (size_t)(n0 + row0) * DM + k0 + cc0 * 8;
      const size_t ga1 = (size_t)(m0 + row1) * DM + k0 + cc1 * 8;
      const size_t gb1 = (size_t)(n0 + row1) * DM + k0 + cc1 * 8;
      async16(Ah + ga0, &sAh[c0 * 8]);
      async16(Bh + gb0, &sBh[c0 * 8]);
      async16(Ah + ga1, &sAh[c1 * 8]);
      async16(Bh + gb1, &sBh[c1 * 8]);
      if constexpr (TERMS == 3) {
        async16(Al + ga0, &sAl[c0 * 8]);
        async16(Bl + gb0, &sBl[c0 * 8]);
        async16(Al + ga1, &sAl[c1 * 8]);
        async16(Bl + gb1, &sBl[c1 * 8]);
      }
    }
    __syncthreads();

    bf16x8 ah[4], bh[4], al[4], bl[4];
#pragma unroll
    for (int i = 0; i < 4; ++i) {
      ah[i] = *(const bf16x8*)&sAh[offA[i]];
      bh[i] = *(const bf16x8*)&sBh[offB[i]];
      if constexpr (TERMS == 3) {
        al[i] = *(const bf16x8*)&sAl[offA[i]];
        bl[i] = *(const bf16x8*)&sBl[offB[i]];
      }
    }
#pragma unroll
    for (int i = 0; i < 4; ++i)
#pragma unroll
      for (int j = 0; j < 4; ++j) {
        acc[i][j] = mfma16(ah[i], bh[j], acc[i][j]);
        if constexpr (TERMS == 3) {
          acc[i][j] = mfma16(ah[i], bl[j], acc[i][j]);
          acc[i][j] = mfma16(al[i], bh[j], acc[i][j]);
        }
      }
    __syncthreads();
  }

  // epilogue; C/D layout: col = lane&15, row = (lane>>4)*4 + reg
#pragma unroll
  for (int i = 0; i < 4; ++i) {
#pragma unroll
    for (int j = 0; j < 4; ++j) {
#pragma unroll
      for (int r = 0; r < 4; ++r) {
        const int gr = m0 + wm + i * 16 + q4 * 4 + r;
        const int gc = n0 + wn + j * 16 + lm;
        const float v = acc[i][j][r];
        if constexpr (OUTMODE == 0) {
          ((__bf16*)C0)[(size_t)gr * DM + gc] = (__bf16)v;
        } else if constexpr (OUTMODE == 1) {
          ((float*)C0)[(size_t)gr * DM + gc] = v;
        } else if constexpr (OUTMODE == 2) {
          const float vs = v * oscale;
          const __bf16 hv = (__bf16)vs;
          ((__bf16*)C0)[(size_t)gr * DM + gc] = hv;
          ((__bf16*)C1)[(size_t)gr * DM + gc] = (__bf16)(vs - (float)hv);
        } else {
          const int bb = gr >> 11, ss = gr & 2047;
          const int hh = gc >> 6, dd = gc & 63;
          ((__bf16*)C0)[(((size_t)(bb * NH + hh) << 6) + dd) * SEQ + ss] = (__bf16)v;
        }
      }
    }
  }
}

// ---------------- flash attention ----------------
// grid: blockIdx.x = bh*32 + qtile ; block = 256 (4 waves, each wave owns 16 q rows)
// Q comes pre-scaled by 0.125*log2(e): scores are base-2 exponents directly.
__global__ void __launch_bounds__(256) flash_kernel(const __bf16* __restrict__ Qh,
                                                    const __bf16* __restrict__ Ql,
                                                    const __bf16* __restrict__ Kh,
                                                    const __bf16* __restrict__ Kl,
                                                    const __bf16* __restrict__ Vt,
                                                    __bf16* __restrict__ Mg) {
  __shared__ __align__(16) __bf16 sQh[64 * 64], sQl[64 * 64];
  __shared__ __align__(16) __bf16 sKh[64 * 64], sKl[64 * 64], sV[64 * 64];
  __shared__ __align__(16) __bf16 sP[4][16 * 72];  // stride 72: 2-way banks, 16B-aligned reads

  const int tid = threadIdx.x;
  const int qt = blockIdx.x & 31;
  const int bh = blockIdx.x >> 5;
  const int b = bh >> 4;
  const int h = bh & 15;
  const int mq0 = b * SEQ + qt * 64;
  const int ch = h * 64;
  const int w = tid >> 6;
  const int lane = tid & 63;
  const int lm = lane & 15;
  const int q4 = lane >> 4;

  // stage Q tile [64 q][64 d], swizzle chunk ^ (row&7)
#pragma unroll
  for (int r = 0; r < 2; ++r) {
    const int c = tid + r * 256;
    const int row = c >> 3, cc = (c & 7) ^ (row & 7);
    const size_t g = (size_t)(mq0 + row) * DM + ch + cc * 8;
    async16(Qh + g, &sQh[c * 8]);
    async16(Ql + g, &sQl[c * 8]);
  }

  floatx4 o[4];
  const floatx4 fz = {0.f, 0.f, 0.f, 0.f};
#pragma unroll
  for (int dt = 0; dt < 4; ++dt) o[dt] = fz;
  float mrow[4], lrow[4];
#pragma unroll
  for (int r = 0; r < 4; ++r) { mrow[r] = -1e30f; lrow[r] = 0.f; }

  __syncthreads();  // Q staged

  // hoist loop-invariant Q fragments into registers
  bf16x8 qh[2], ql[2];
#pragma unroll
  for (int ks = 0; ks < 2; ++ks) {
    const int rq = w * 16 + lm;
    const int oq = rq * 64 + (((ks * 4 + q4) ^ (rq & 7)) << 3);
    qh[ks] = *(const bf16x8*)&sQh[oq];
    ql[ks] = *(const bf16x8*)&sQl[oq];
  }

  for (int it = 0; it < 32; ++it) {
    const int kt0 = it * 64;
#pragma unroll
    for (int r = 0; r < 2; ++r) {
      const int c = tid + r * 256;
      const int row = c >> 3, cc = (c & 7) ^ (row & 7);
      const size_t gk = (size_t)(b * SEQ + kt0 + row) * DM + ch + cc * 8;
      async16(Kh + gk, &sKh[c * 8]);
      async16(Kl + gk, &sKl[c * 8]);
      const size_t gv = ((size_t)(bh * 64 + row)) * SEQ + kt0 + cc * 8;
      async16(Vt + gv, &sV[c * 8]);
    }
    __syncthreads();

    // scores: S[16 q x 64 key] per wave, 3-term, already in log2 domain
    floatx4 s[4];
#pragma unroll
    for (int nt = 0; nt < 4; ++nt) s[nt] = fz;
#pragma unroll
    for (int ks = 0; ks < 2; ++ks) {
#pragma unroll
      for (int nt = 0; nt < 4; ++nt) {
        const int rk = nt * 16 + lm;
        const int ok = rk * 64 + (((ks * 4 + q4) ^ (rk & 7)) << 3);
        const bf16x8 kh = *(const bf16x8*)&sKh[ok];
        const bf16x8 kl = *(const bf16x8*)&sKl[ok];
        s[nt] = mfma16(qh[ks], kh, s[nt]);
        s[nt] = mfma16(qh[ks], kl, s[nt]);
        s[nt] = mfma16(ql[ks], kh, s[nt]);
      }
    }

    // online softmax (base-2). Rows: q = q4*4 + r (C layout), reduce over 16 lanes via DPP.
    float mnew[4];
    bool upd = false;
#pragma unroll
    for (int r = 0; r < 4; ++r) {
      float mx = fmaxf(fmaxf(s[0][r], s[1][r]), fmaxf(s[2][r], s[3][r]));
      mx = red16_max(mx);
      mnew[r] = fmaxf(mrow[r], mx);
      upd = upd || (mnew[r] > mrow[r]);
    }
    if (__ballot(upd)) {
#pragma unroll
      for (int r = 0; r < 4; ++r) {
        const float a = __builtin_amdgcn_exp2f(mrow[r] - mnew[r]);
        lrow[r] *= a;
        mrow[r] = mnew[r];
#pragma unroll
        for (int dt = 0; dt < 4; ++dt) o[dt][r] *= a;
      }
    }
#pragma unroll
    for (int r = 0; r < 4; ++r) {
      float p[4];
#pragma unroll
      for (int nt = 0; nt < 4; ++nt) p[nt] = __builtin_amdgcn_exp2f(s[nt][r] - mrow[r]);
      float sum = (p[0] + p[1]) + (p[2] + p[3]);
      sum = red16_sum(sum);
      lrow[r] += sum;
      const int qrow = q4 * 4 + r;
#pragma unroll
      for (int nt = 0; nt < 4; ++nt)
        sP[w][qrow * 72 + nt * 16 + lm] = (__bf16)p[nt];
    }

    // PV: A = P (own wave's LDS), B = V^T tile
#pragma unroll
    for (int ks = 0; ks < 2; ++ks) {
      const bf16x8 a = *(const bf16x8*)&sP[w][lm * 72 + ((ks * 4 + q4) << 3)];
#pragma unroll
      for (int dt = 0; dt < 4; ++dt) {
        const int rv = dt * 16 + lm;
        const int ov = rv * 64 + (((ks * 4 + q4) ^ (rv & 7)) << 3);
        const bf16x8 bv = *(const bf16x8*)&sV[ov];
        o[dt] = mfma16(a, bv, o[dt]);
      }
    }
    __syncthreads();
  }

  // epilogue: normalize and store merged [B*S, D] bf16
#pragma unroll
  for (int r = 0; r < 4; ++r) {
    const float inv = __builtin_amdgcn_rcpf(lrow[r]);
    const int gr = mq0 + w * 16 + q4 * 4 + r;
#pragma unroll
    for (int dt = 0; dt < 4; ++dt)
      Mg[(size_t)gr * DM + ch + dt * 16 + lm] = (__bf16)(o[dt][r] * inv);
  }
}

// ---------------- launch ----------------

extern "C" void kernel_launch(void* const* d_in, const int* in_sizes, int n_in,
                              void* d_out, int out_size, void* d_ws, size_t ws_size,
                              hipStream_t stream) {
  (void)in_sizes; (void)n_in; (void)out_size; (void)ws_size;
  const float* x  = (const float*)d_in[0];
  const float* Wq = (const float*)d_in[1];
  const float* Wk = (const float*)d_in[2];
  const float* Wv = (const float*)d_in[3];
  const float* fc = (const float*)d_in[4];
  float* out = (float*)d_out;

  char* base = (char*)d_ws;
  const size_t XB = (size_t)MROWS * DM * 2;  // 16 MiB
  const size_t WB = (size_t)DM * DM * 2;     // 2 MiB
  __bf16* xh  = (__bf16*)(base);
  __bf16* xl  = (__bf16*)(base + XB);
  __bf16* wqh = (__bf16*)(base + 2 * XB);
  __bf16* wql = (__bf16*)(base + 2 * XB + WB);
  __bf16* wkh = (__bf16*)(base + 2 * XB + 2 * WB);
  __bf16* wkl = (__bf16*)(base + 2 * XB + 3 * WB);
  __bf16* wvh = (__bf16*)(base + 2 * XB + 4 * WB);
  __bf16* fch = (__bf16*)(base + 2 * XB + 5 * WB);
  __bf16* Qh  = (__bf16*)(base + 2 * XB + 6 * WB);
  __bf16* Ql  = (__bf16*)(base + 3 * XB + 6 * WB);
  __bf16* Kh  = (__bf16*)(base + 4 * XB + 6 * WB);
  __bf16* Kl  = (__bf16*)(base + 5 * XB + 6 * WB);
  __bf16* Vt  = xl;  // xl dead after K projection
  __bf16* Mg  = xh;  // xh dead after V projection

  split_x_kernel<<<dim3(8192), dim3(256), 0, stream>>>(x, xh, xl);
  wtrans_kernel<<<dim3(1024), dim3(256), 0, stream>>>(Wq, wqh, wql);
  wtrans_kernel<<<dim3(1024), dim3(256), 0, stream>>>(Wk, wkh, wkl);
  wtrans_kernel<<<dim3(1024), dim3(256), 0, stream>>>(Wv, wvh, (__bf16*)nullptr);
  wtrans_kernel<<<dim3(1024), dim3(256), 0, stream>>>(fc, fch, (__bf16*)nullptr);

  // Q pre-scaled by 0.125*log2(e) so flash softmax runs in base-2 with no per-score mul
  gemm_nt<3, 2><<<dim3(512), dim3(256), 0, stream>>>(xh, xl, wqh, wql, (void*)Qh, (void*)Ql, QSCALE);
  gemm_nt<3, 2><<<dim3(512), dim3(256), 0, stream>>>(xh, xl, wkh, wkl, (void*)Kh, (void*)Kl, 1.0f);
  gemm_nt<1, 3><<<dim3(512), dim3(256), 0, stream>>>(xh, (const __bf16*)nullptr, wvh,
                                                     (const __bf16*)nullptr, (void*)Vt, (void*)nullptr, 1.0f);

  flash_kernel<<<dim3(2048), dim3(256), 0, stream>>>(Qh, Ql, Kh, Kl, Vt, Mg);

  gemm_nt<1, 1><<<dim3(512), dim3(256), 0, stream>>>(Mg, (const __bf16*)nullptr, fch,
                                                     (const __bf16*)nullptr, (void*)out, (void*)nullptr, 1.0f);
}